// Round 1
// baseline (744.070 us; speedup 1.0000x reference)
//
#include <hip/hip_runtime.h>

// ---- filter / neuron constants (double, matching the Python reference) ----
#define EMD 0.8824969025845955      // exp(-1/8)
#define ESD 0.6065306597126334      // exp(-1/2)
#define A1C ((float)(EMD + ESD))                    // y[t-1] coeff
#define A2C ((float)(-(EMD * ESD)))                 // y[t-2] coeff
#define BC  ((float)((8.0 / 6.0) * (EMD - ESD)))    // x[t] coeff (ETA=8/6)
#define EMF ((float)EMD)                            // reset decay

// B=64, T=300. Layers: 300 -> 500 -> 200 -> 500 -> 300.

// ---------------------------------------------------------------------------
// GEMM: C[b,o,t] = sum_i W[o,i] * X[b,i,t]
// X: [B,K,T] (T contiguous), W: [O,K], C: [B,O,T]
// 64x64 tile per 256-thread block, 4x4 microtile/thread, KC=16 LDS staging.
// ---------------------------------------------------------------------------
#define KC 16

__global__ __launch_bounds__(256) void gemm_snn(
    const float* __restrict__ X, const float* __restrict__ W,
    float* __restrict__ C, int K, int O, int T)
{
    __shared__ float Ws[KC][68];   // [k][o_local], +4 pad keeps 16B align, breaks bank stride
    __shared__ float Xs[KC][68];   // [k][t_local]

    const int tx  = threadIdx.x;           // 0..15
    const int ty  = threadIdx.y;           // 0..15
    const int tid = ty * 16 + tx;
    const int t0  = blockIdx.x * 64;
    const int o0  = blockIdx.y * 64;
    const int b   = blockIdx.z;
    const float* Xb = X + (size_t)b * K * T;

    float acc[4][4] = {};

    for (int k0 = 0; k0 < K; k0 += KC) {
        // stage W tile: Ws[kl][ol] = W[o0+ol][k0+kl]
        {
            const int kl = tid & 15;
            const int orow = tid >> 4;
#pragma unroll
            for (int r = 0; r < 4; r++) {
                const int ol = orow + r * 16;
                const int o = o0 + ol, k = k0 + kl;
                Ws[kl][ol] = (o < O && k < K) ? W[(size_t)o * K + k] : 0.0f;
            }
        }
        // stage X tile: Xs[kl][tl] = X[b][k0+kl][t0+tl]  (coalesced over t)
        {
            const int tl = tid & 63;
            const int krow = tid >> 6;
#pragma unroll
            for (int r = 0; r < 4; r++) {
                const int kl = krow + r * 4;
                const int k = k0 + kl, t = t0 + tl;
                Xs[kl][tl] = (k < K && t < T) ? Xb[(size_t)k * T + t] : 0.0f;
            }
        }
        __syncthreads();
#pragma unroll
        for (int k = 0; k < KC; k++) {
            const float a0 = Ws[k][ty * 4 + 0], a1 = Ws[k][ty * 4 + 1];
            const float a2 = Ws[k][ty * 4 + 2], a3 = Ws[k][ty * 4 + 3];
            const float x0 = Xs[k][tx * 4 + 0], x1 = Xs[k][tx * 4 + 1];
            const float x2 = Xs[k][tx * 4 + 2], x3 = Xs[k][tx * 4 + 3];
            acc[0][0] += a0 * x0; acc[0][1] += a0 * x1; acc[0][2] += a0 * x2; acc[0][3] += a0 * x3;
            acc[1][0] += a1 * x0; acc[1][1] += a1 * x1; acc[1][2] += a1 * x2; acc[1][3] += a1 * x3;
            acc[2][0] += a2 * x0; acc[2][1] += a2 * x1; acc[2][2] += a2 * x2; acc[2][3] += a2 * x3;
            acc[3][0] += a3 * x0; acc[3][1] += a3 * x1; acc[3][2] += a3 * x2; acc[3][3] += a3 * x3;
        }
        __syncthreads();
    }

    float* Cb = C + (size_t)b * O * T;
    const bool full_t = (t0 + 64 <= T);
#pragma unroll
    for (int i = 0; i < 4; i++) {
        const int o = o0 + ty * 4 + i;
        if (o < O) {
            float* Crow = Cb + (size_t)o * T + t0;
            if (full_t) {
                *reinterpret_cast<float4*>(Crow + tx * 4) =
                    make_float4(acc[i][0], acc[i][1], acc[i][2], acc[i][3]);
            } else {
#pragma unroll
                for (int j = 0; j < 4; j++) {
                    const int t = t0 + tx * 4 + j;
                    if (t < T) Crow[tx * 4 + j] = acc[i][j];
                }
            }
        }
    }
}

// ---------------------------------------------------------------------------
// Fused IIR + bias + LIF (in-place): C holds raw currents [B,O,T]; after this
// kernel it holds spikes. IIR commutes with the GEMM since coefficients are
// uniform across features (read scalar from element 0 of the coeff arrays).
// One thread per (b,o) chain, sequential over T, float4 I/O.
// ---------------------------------------------------------------------------
__global__ __launch_bounds__(256) void lif_snn(
    float* __restrict__ C, const float* __restrict__ bias,
    const float* __restrict__ a1p, const float* __restrict__ a2p,
    const float* __restrict__ bp, int BO, int O, int T4)
{
    const int idx = blockIdx.x * 256 + threadIdx.x;
    if (idx >= BO) return;
    const float A1 = a1p[0], A2 = a2p[0], Bc = bp[0];
    const float bi = bias[idx % O];
    float4* row = reinterpret_cast<float4*>(C) + (size_t)idx * T4;
    float y1 = 0.0f, y2 = 0.0f, r = 0.0f;
    for (int q = 0; q < T4; q++) {
        float4 x = row[q];
        float y, v, s;
        y = A1 * y1 + A2 * y2 + Bc * x.x; y2 = y1; y1 = y;
        v = y + bi + r; s = (v >= 1.0f) ? 1.0f : 0.0f; r = r * EMF - s; x.x = s;
        y = A1 * y1 + A2 * y2 + Bc * x.y; y2 = y1; y1 = y;
        v = y + bi + r; s = (v >= 1.0f) ? 1.0f : 0.0f; r = r * EMF - s; x.y = s;
        y = A1 * y1 + A2 * y2 + Bc * x.z; y2 = y1; y1 = y;
        v = y + bi + r; s = (v >= 1.0f) ? 1.0f : 0.0f; r = r * EMF - s; x.z = s;
        y = A1 * y1 + A2 * y2 + Bc * x.w; y2 = y1; y1 = y;
        v = y + bi + r; s = (v >= 1.0f) ? 1.0f : 0.0f; r = r * EMF - s; x.w = s;
        row[q] = x;
    }
}

// ---------------------------------------------------------------------------
// Output filter: filt = IIR(s4), fixed constants. One thread per (b,f) chain.
// ---------------------------------------------------------------------------
__global__ __launch_bounds__(256) void iir_out(
    const float* __restrict__ S, float* __restrict__ Y, int BF, int T4)
{
    const int idx = blockIdx.x * 256 + threadIdx.x;
    if (idx >= BF) return;
    const float4* src = reinterpret_cast<const float4*>(S) + (size_t)idx * T4;
    float4* dst = reinterpret_cast<float4*>(Y) + (size_t)idx * T4;
    float y1 = 0.0f, y2 = 0.0f;
    for (int q = 0; q < T4; q++) {
        const float4 x = src[q];
        float4 o;
        float y;
        y = A1C * y1 + A2C * y2 + BC * x.x; y2 = y1; y1 = y; o.x = y;
        y = A1C * y1 + A2C * y2 + BC * x.y; y2 = y1; y1 = y; o.y = y;
        y = A1C * y1 + A2C * y2 + BC * x.z; y2 = y1; y1 = y; o.z = y;
        y = A1C * y1 + A2C * y2 + BC * x.w; y2 = y1; y1 = y; o.w = y;
        dst[q] = o;
    }
}

// ---------------------------------------------------------------------------
extern "C" void kernel_launch(void* const* d_in, const int* in_sizes, int n_in,
                              void* d_out, int out_size, void* d_ws, size_t ws_size,
                              hipStream_t stream)
{
    const float* inputs = (const float*)d_in[0];           // [64,300,300] binary
    const float* a1_1 = (const float*)d_in[1];
    const float* a2_1 = (const float*)d_in[2];
    const float* b_1  = (const float*)d_in[3];
    const float* W1   = (const float*)d_in[4];             // [500,300]
    const float* bias1= (const float*)d_in[5];
    const float* a1_2 = (const float*)d_in[6];
    const float* a2_2 = (const float*)d_in[7];
    const float* b_2  = (const float*)d_in[8];
    const float* W2   = (const float*)d_in[9];             // [200,500]
    const float* bias2= (const float*)d_in[10];
    const float* a1_3 = (const float*)d_in[11];
    const float* a2_3 = (const float*)d_in[12];
    const float* b_3  = (const float*)d_in[13];
    const float* W3   = (const float*)d_in[14];            // [500,200]
    const float* bias3= (const float*)d_in[15];
    const float* a1_4 = (const float*)d_in[16];
    const float* a2_4 = (const float*)d_in[17];
    const float* b_4  = (const float*)d_in[18];
    const float* W4   = (const float*)d_in[19];            // [300,500]
    const float* bias4= (const float*)d_in[20];

    const int B = 64, T = 300, T4 = T / 4;

    float* ws = (float*)d_ws;
    float* c1 = ws;                         // [64,500,300] = 9.6M floats (also s1, s3)
    float* c2 = ws + 9600000;               // [64,200,300] = 3.84M floats (also s2)
    float* out = (float*)d_out;
    float* s4   = out;                      // [64,300,300]
    float* filt = out + 5760000;            // [64,300,300]

    const dim3 blk(16, 16);

    // Layer 1: 300 -> 500
    gemm_snn<<<dim3(5, 8, B), blk, 0, stream>>>(inputs, W1, c1, 300, 500, T);
    lif_snn<<<(B * 500 + 255) / 256, 256, 0, stream>>>(c1, bias1, a1_1, a2_1, b_1, B * 500, 500, T4);
    // Layer 2: 500 -> 200
    gemm_snn<<<dim3(5, 4, B), blk, 0, stream>>>(c1, W2, c2, 500, 200, T);
    lif_snn<<<(B * 200 + 255) / 256, 256, 0, stream>>>(c2, bias2, a1_2, a2_2, b_2, B * 200, 200, T4);
    // Layer 3: 200 -> 500 (reuse c1 buffer; s1 dead)
    gemm_snn<<<dim3(5, 8, B), blk, 0, stream>>>(c2, W3, c1, 200, 500, T);
    lif_snn<<<(B * 500 + 255) / 256, 256, 0, stream>>>(c1, bias3, a1_3, a2_3, b_3, B * 500, 500, T4);
    // Layer 4: 500 -> 300, currents straight into d_out, spikes in-place
    gemm_snn<<<dim3(5, 5, B), blk, 0, stream>>>(c1, W4, s4, 500, 300, T);
    lif_snn<<<(B * 300 + 255) / 256, 256, 0, stream>>>(s4, bias4, a1_4, a2_4, b_4, B * 300, 300, T4);
    // Output filter
    iir_out<<<(B * 300 + 255) / 256, 256, 0, stream>>>(s4, filt, B * 300, T4);
}